// Round 6
// baseline (9173.525 us; speedup 1.0000x reference)
//
#include <hip/hip_runtime.h>

constexpr int kB = 64;
constexpr int kT = 1024;
constexpr int kC = 128;
constexpr int kH = 512;

constexpr int kGroups   = 8;    // batch groups (8 batches each)
constexpr int kWgPerGrp = 64;   // wgs per group (8 cols each)
constexpr int kRows     = 8;    // batches per group
constexpr int kWStride  = 520;  // w_hh LDS row: 512 data + 8 pad floats
constexpr int kHStride  = 652;  // hbuf row: 512 h + 128 x + 12 pad floats

#define SCOPE_AGENT __HIP_MEMORY_SCOPE_AGENT

__device__ __forceinline__ float sigmoidf_(float v) {
    return 1.0f / (1.0f + __expf(-v));
}

// Persistent GRU. 512 wgs x 128 threads (2 waves), 2 wgs/CU (70,784 B LDS each).
// 8 groups x 64 wgs; grp = wg>>6 so co-resident block pairs (k, k+256) belong
// to DIFFERENT groups -> one group's compute hides the other's barrier/staging
// latency on the shared CU. Group g owns batches [g*8, g*8+8); wg owns output
// columns [jb*8, jb*8+8).
// h-exchange through hs_out (R5-proven): finisher does a relaxed agent-scope
// atomic store (MALL-visible); next step stages hs_out[:, t-1, :] with plain
// coalesced float4 loads — fresh addresses each step, so no cache can be stale.
// Ordering: atomic store -> __syncthreads (vmcnt drain) -> flag store; reader:
// poll flags -> plain load.
// w_hh slice LDS-stationary; w_ih slice in registers. hbuf = [h(512)|x(128)].
// Thread map: tid = jp(2b) | s(5b): jp = j-pair (t_j=2), s = K-slice (lane
// bits 0-4), t_b=8 (all rows). Strided K-split k4 = s + 32m, m in [0,4);
// x-part covered by f4 index s. n-gate keeps separate h/x accumulators.
// Reduction over s: reduce-scatter over xor{8,4,2,1} (scatter (row,col)
// ownership, o = s&15) + one xor-16 butterfly on the 4 gate values.
// Per-step sync: all-report flag barrier (64 flags, polled by wave 0).
__global__ __launch_bounds__(128, 1)
void gru_seq_kernel(const float* __restrict__ x,
                    const float* __restrict__ h0,
                    const float* __restrict__ w_ih,
                    const float* __restrict__ w_hh,
                    const float* __restrict__ b_ih,
                    const float* __restrict__ b_hh,
                    float* __restrict__ hs_out,   // d_out, [B,T,H]; also h-exchange
                    float* __restrict__ h_final,  // d_out + B*T*H
                    unsigned* __restrict__ flags) // d_ws: 8 x 64 uints
{
    const int wg  = blockIdx.x;
    const int grp = wg >> 6;           // 0..7 (pairing: k and k+256 differ)
    const int jb  = wg & 63;           // 0..63
    const int tid = threadIdx.x;
    const int jp  = tid >> 5;          // 0..3 (j-pair)
    const int s   = tid & 31;          // K-slice (lane bits 0-4)
    const int b0  = grp * kRows;

    __shared__ float wh[3][8][kWStride];     // 49,920 B (w_hh rows, this j-block)
    __shared__ float hbuf[kRows][kHStride];  // 20,864 B ([h | x] per batch row)

    // ---- one-time w_hh staging into LDS ----
    for (int idx = tid; idx < 3 * 8 * 128; idx += 128) {
        const int g   = idx >> 10;
        const int col = (idx >> 7) & 7;
        const int k4  = idx & 127;
        *(float4*)&wh[g][col][k4 * 4] =
            *(const float4*)&w_hh[((size_t)(g * kH + jb * 8 + col)) * kH + k4 * 4];
    }

    // ---- one-time w_ih slice into registers: wiR[gate][jj] at x-f4 = s ----
    float4 wiR[3][2];
    #pragma unroll
    for (int g = 0; g < 3; ++g)
        #pragma unroll
        for (int jj = 0; jj < 2; ++jj)
            wiR[g][jj] = *(const float4*)
                &w_ih[((size_t)(g * kH + jb * 8 + jp * 2 + jj)) * kC + s * 4];

    // biases for this thread's finish output (finishers are s<16; jj = s&1)
    const int jg_f = jb * 8 + jp * 2 + (s & 1);
    const float brz = b_ih[jg_f]          + b_hh[jg_f];
    const float bzz = b_ih[kH + jg_f]     + b_hh[kH + jg_f];
    const float bxn = b_ih[2 * kH + jg_f];
    const float bhn = b_hh[2 * kH + jg_f];

    unsigned* myflag = flags + grp * kWgPerGrp + jb;
    const unsigned* pollflag = flags + grp * kWgPerGrp + (tid & 63);

    // all-report barrier: store own epoch flag, wave 0 polls all 64
    auto group_barrier = [&](unsigned e) {
        __syncthreads();   // vmcnt(0) drain: prior (atomic) stores MALL-visible
        if (tid < 64) {
            if (tid == 0)
                __hip_atomic_store(myflag, e, __ATOMIC_RELAXED, SCOPE_AGENT);
            unsigned v;
            do {
                v = __hip_atomic_load(pollflag, __ATOMIC_RELAXED, SCOPE_AGENT);
            } while (__any((int)(v < e)));
        }
        __syncthreads();
    };

    for (int t = 0; t < kT; ++t) {
        // ---- stage h rows: PLAIN float4 loads, 8 per thread ----
        {
            #pragma unroll
            for (int q = 0; q < 8; ++q) {
                const int idx = tid + q * 128;     // 0..1023
                const int row = idx >> 7;          // 0..7
                const int f4  = idx & 127;
                float4 v;
                if (t == 0)
                    v = *(const float4*)&h0[(size_t)(b0 + row) * kH + f4 * 4];
                else
                    v = *(const float4*)
                        &hs_out[((size_t)(b0 + row) * kT + (t - 1)) * kH + f4 * 4];
                *(float4*)&hbuf[row][f4 * 4] = v;
            }
        }
        if (t == 0) {   // steady-state x is prefetched at the end of prev iter
            #pragma unroll
            for (int q = 0; q < 2; ++q) {
                const int idx = tid + q * 128;     // 0..255
                const int row = idx >> 5;          // 0..7
                const int f4i = idx & 31;
                *(float4*)&hbuf[row][512 + f4i * 4] =
                    *(const float4*)&x[((size_t)(b0 + row) * kT + 0) * kC + f4i * 4];
            }
        }
        __syncthreads();

        // ---- gate dots: acc[{r,z,n_h,n_x}][8 rows][2 j] ----
        float acc[4][8][2];
        #pragma unroll
        for (int g = 0; g < 4; ++g)
            #pragma unroll
            for (int i = 0; i < 8; ++i) {
                acc[g][i][0] = 0.f; acc[g][i][1] = 0.f;
            }

        const float* hbase = &hbuf[0][s * 4];
        const float* wbase = &wh[0][jp * 2][s * 4];

        #pragma unroll
        for (int m = 0; m < 4; ++m) {         // h-part: k4 = s + 32m
            const int off = m * 128;
            float4 h4[8];
            #pragma unroll
            for (int i = 0; i < 8; ++i)
                h4[i] = *(const float4*)(hbase + i * kHStride + off);
            #pragma unroll
            for (int g = 0; g < 3; ++g) {
                #pragma unroll
                for (int jj = 0; jj < 2; ++jj) {
                    const float4 w4 = *(const float4*)(wbase + (g * 8 + jj) * kWStride + off);
                    #pragma unroll
                    for (int i = 0; i < 8; ++i)
                        acc[g][i][jj] += h4[i].x * w4.x + h4[i].y * w4.y
                                       + h4[i].z * w4.z + h4[i].w * w4.w;
                }
            }
        }
        {   // x-part: x-f4 = s (weights in registers)
            float4 x4v[8];
            #pragma unroll
            for (int i = 0; i < 8; ++i)
                x4v[i] = *(const float4*)(&hbuf[i][512 + s * 4]);
            #pragma unroll
            for (int g = 0; g < 3; ++g) {
                const int ga = (g == 2) ? 3 : g;   // x-side n goes to acc[3]
                #pragma unroll
                for (int jj = 0; jj < 2; ++jj) {
                    const float4 w4 = wiR[g][jj];
                    #pragma unroll
                    for (int i = 0; i < 8; ++i)
                        acc[ga][i][jj] += x4v[i].x * w4.x + x4v[i].y * w4.y
                                        + x4v[i].z * w4.z + x4v[i].w * w4.w;
                }
            }
        }

        // ---- reduce-scatter over s: xor{8,4,2,1} scatter + xor16 butterfly.
        // Lane s ends with full sums for output o = s&15 (row = o>>1, jj = o&1).
        const bool b3 = (s >> 3) & 1;
        const bool b2 = (s >> 2) & 1;
        const bool b1 = (s >> 1) & 1;
        const bool b0b = s & 1;

        float A[4][4][2];
        #pragma unroll
        for (int g = 0; g < 4; ++g)
            #pragma unroll
            for (int ii = 0; ii < 4; ++ii)
                #pragma unroll
                for (int jj = 0; jj < 2; ++jj) {
                    const float keep = b3 ? acc[g][4 + ii][jj] : acc[g][ii][jj];
                    const float send = b3 ? acc[g][ii][jj] : acc[g][4 + ii][jj];
                    A[g][ii][jj] = keep + __shfl_xor(send, 8);
                }
        float Bv[4][2][2];
        #pragma unroll
        for (int g = 0; g < 4; ++g)
            #pragma unroll
            for (int ii = 0; ii < 2; ++ii)
                #pragma unroll
                for (int jj = 0; jj < 2; ++jj) {
                    const float keep = b2 ? A[g][2 + ii][jj] : A[g][ii][jj];
                    const float send = b2 ? A[g][ii][jj] : A[g][2 + ii][jj];
                    Bv[g][ii][jj] = keep + __shfl_xor(send, 4);
                }
        float Cv[4][2];
        #pragma unroll
        for (int g = 0; g < 4; ++g)
            #pragma unroll
            for (int jj = 0; jj < 2; ++jj) {
                const float keep = b1 ? Bv[g][1][jj] : Bv[g][0][jj];
                const float send = b1 ? Bv[g][0][jj] : Bv[g][1][jj];
                Cv[g][jj] = keep + __shfl_xor(send, 2);
            }
        float Dv[4];
        #pragma unroll
        for (int g = 0; g < 4; ++g) {
            const float keep = b0b ? Cv[g][1] : Cv[g][0];
            const float send = b0b ? Cv[g][0] : Cv[g][1];
            Dv[g] = keep + __shfl_xor(send, 1);
            Dv[g] += __shfl_xor(Dv[g], 16);
        }

        __syncthreads();   // all compute reads of hbuf x-section done

        // ---- prefetch x for step t+1 into hbuf x-section ----
        if (t + 1 < kT) {
            #pragma unroll
            for (int q = 0; q < 2; ++q) {
                const int idx = tid + q * 128;
                const int row = idx >> 5;
                const int f4i = idx & 31;
                *(float4*)&hbuf[row][512 + f4i * 4] =
                    *(const float4*)&x[((size_t)(b0 + row) * kT + (t + 1)) * kC + f4i * 4];
            }
        }

        // ---- finish: lane s<16 owns output (row = s>>1, jj = s&1) ----
        if (s < 16) {
            const int   bloc = s >> 1;
            const int   bg   = b0 + bloc;
            const float rg   = sigmoidf_(Dv[0] + brz);
            const float zg   = sigmoidf_(Dv[1] + bzz);
            const float ng   = tanhf(Dv[3] + bxn + rg * (Dv[2] + bhn));
            const float hold = hbuf[bloc][jg_f];
            const float hnew = (1.f - zg) * ng + zg * hold;

            // single h-publish: atomic (MALL-visible) store into hs_out
            __hip_atomic_store(&hs_out[((size_t)bg * kT + t) * kH + jg_f], hnew,
                               __ATOMIC_RELAXED, SCOPE_AGENT);
            if (t == kT - 1) h_final[(size_t)bg * kH + jg_f] = hnew;
        }

        group_barrier((unsigned)(t + 1));
    }
}

// In-place post projection: out[b,t,:] = relu(hs[b,t,:] @ w_post^T + b_post).
__global__ __launch_bounds__(256, 1)
void post_kernel(const float* __restrict__ w_post,
                 const float* __restrict__ b_post,
                 float* __restrict__ out)
{
    __shared__ float hbuf[16][kH];
    const int tid = threadIdx.x;
    const size_t row0 = (size_t)blockIdx.x * 16;

    const float4* src = (const float4*)(out + row0 * kH);
    float4* hb4 = (float4*)hbuf;
    for (int i = tid; i < 16 * kH / 4; i += 256) hb4[i] = src[i];
    __syncthreads();

    for (int pass = 0; pass < 2; ++pass) {
        const int d = tid + pass * 256;
        const float4* wrow = (const float4*)(w_post + (size_t)d * kH);
        float acc[16];
        #pragma unroll
        for (int m = 0; m < 16; ++m) acc[m] = 0.f;
        for (int k4 = 0; k4 < kH / 4; ++k4) {
            const float4 w4 = wrow[k4];
            #pragma unroll
            for (int m = 0; m < 16; ++m) {
                const float4 h4 = *(const float4*)&hbuf[m][k4 * 4];
                acc[m] += h4.x * w4.x + h4.y * w4.y + h4.z * w4.z + h4.w * w4.w;
            }
        }
        const float bp = b_post[d];
        #pragma unroll
        for (int m = 0; m < 16; ++m) {
            out[(row0 + m) * kH + d] = fmaxf(acc[m] + bp, 0.f);
        }
    }
}

extern "C" void kernel_launch(void* const* d_in, const int* in_sizes, int n_in,
                              void* d_out, int out_size, void* d_ws, size_t ws_size,
                              hipStream_t stream) {
    const float* x      = (const float*)d_in[0];
    const float* h0     = (const float*)d_in[1];
    const float* w_ih   = (const float*)d_in[2];
    const float* w_hh   = (const float*)d_in[3];
    const float* b_ih   = (const float*)d_in[4];
    const float* b_hh   = (const float*)d_in[5];
    const float* w_post = (const float*)d_in[6];
    const float* b_post = (const float*)d_in[7];

    float* out     = (float*)d_out;
    float* h_final = out + (size_t)kB * kT * kH;

    unsigned* flags = (unsigned*)d_ws;   // 8 x 64 uints = 2 KB

    // flags must start at 0 every launch (d_ws is not re-poisoned per replay)
    hipMemsetAsync(d_ws, 0, 4096, stream);

    void* args[] = { (void*)&x, (void*)&h0, (void*)&w_ih, (void*)&w_hh,
                     (void*)&b_ih, (void*)&b_hh, (void*)&out, (void*)&h_final,
                     (void*)&flags };
    // Cooperative launch for guaranteed co-residency (512 wgs, 2/CU by LDS:
    // 2 x 70,784 = 141,568 <= 160K); fall back to plain launch if refused.
    hipError_t err = hipLaunchCooperativeKernel((void*)gru_seq_kernel,
                                                dim3(512), dim3(128),
                                                args, 0, stream);
    if (err != hipSuccess) {
        gru_seq_kernel<<<dim3(512), dim3(128), 0, stream>>>(
            x, h0, w_ih, w_hh, b_ih, b_hh, out, h_final, flags);
    }

    post_kernel<<<dim3(kB * kT / 16), dim3(256), 0, stream>>>(w_post, b_post, out);
}

// Round 7
// 6949.825 us; speedup vs baseline: 1.3200x; 1.3200x over previous
//
#include <hip/hip_runtime.h>

constexpr int kB = 64;
constexpr int kT = 1024;
constexpr int kC = 128;
constexpr int kH = 512;

constexpr int kGroups   = 16;   // batch groups (4 batches each)
constexpr int kWgPerGrp = 32;   // wgs per group (16 cols each)
constexpr int kRows     = 4;    // batches per group
constexpr int kHStride  = 652;  // hbuf row: 512 h + 128 x + 12 pad floats

#define SCOPE_AGENT __HIP_MEMORY_SCOPE_AGENT

__device__ __forceinline__ float sigmoidf_(float v) {
    return 1.0f / (1.0f + __expf(-v));
}

// Persistent GRU. 512 wgs x 256 threads (4 waves), 2 wgs/CU (10.4KB LDS each).
// 16 groups x 32 wgs. Mapping: xcd = wg&7, q = wg>>3; grp = xcd*2 + (q&1);
// jb = q>>1. Under round-robin block->XCD placement each XCD hosts exactly
// groups {2x, 2x+1} (L2 locality, R5-proven) and each CU hosts one wg of each
// (2 waves/SIMD from different groups -> one group's barrier chain hides under
// the other group's compute). Correctness does NOT depend on placement.
// Group g owns batches [g*4, g*4+4); wg owns output columns [jb*16, jb*16+16).
// h-exchange through hs_out (R5-proven): finishers publish with relaxed
// agent-scope atomic stores (MALL-visible); consumers stage hs_out[:, t-1, :]
// with plain coalesced float4 loads — addresses are fresh every step, so no
// cache can hold a stale copy. Ordering: atomic store -> __syncthreads (vmcnt
// drain) -> flag store; reader: poll flags -> plain load.
// ALL weights in registers: whR[m][g][jj] (24 f4) + wiR[g][jj] (6 f4) per
// thread; LDS holds only hbuf = [h(512) | x(128)] per batch row.
// Thread map: tid = jp(3b) | s(5b): jp in [0,8) j-pair (t_j=2), s = K-slice.
// Strided K-split: h-k4 = s + 32m, m in [0,4); x-k4 = s. n-gate keeps separate
// h/x accumulators (reference: n = tanh(xn + r*hn)).
// Reduction over s: reduce-scatter xor{8,4,2} (owner bits: row=b3*2+b2, jj=b1)
// + full butterflies xor{16,1}; finishers are even lanes s<16.
// Per-step sync: all-report flag barrier (32 flags, polled by lanes tid<32).
__global__ __launch_bounds__(256, 2)
void gru_seq_kernel(const float* __restrict__ x,
                    const float* __restrict__ h0,
                    const float* __restrict__ w_ih,
                    const float* __restrict__ w_hh,
                    const float* __restrict__ b_ih,
                    const float* __restrict__ b_hh,
                    float* __restrict__ hs_out,   // d_out, [B,T,H]; also h-exchange
                    float* __restrict__ h_final,  // d_out + B*T*H
                    unsigned* __restrict__ flags) // d_ws: 16 x 32 uints
{
    const int wg  = blockIdx.x;
    const int q   = wg >> 3;
    const int grp = ((wg & 7) << 1) | (q & 1);   // 0..15
    const int jb  = q >> 1;                      // 0..31
    const int tid = threadIdx.x;
    const int jp  = tid >> 5;                    // 0..7 (j-pair)
    const int s   = tid & 31;                    // K-slice (lane bits 0-4)
    const int b0  = grp * kRows;

    __shared__ float hbuf[kRows][kHStride];      // 10,432 B ([h | x] per row)

    // ---- one-time weight loads into REGISTERS ----
    const float4* w_hh4 = (const float4*)w_hh;
    const float4* w_ih4 = (const float4*)w_ih;
    float4 whR[4][3][2];   // [m][gate][jj]
    #pragma unroll
    for (int m = 0; m < 4; ++m)
        #pragma unroll
        for (int g = 0; g < 3; ++g)
            #pragma unroll
            for (int jj = 0; jj < 2; ++jj)
                whR[m][g][jj] =
                    w_hh4[((size_t)(g * kH + jb * 16 + jp * 2 + jj)) * (kH / 4)
                          + s + 32 * m];
    float4 wiR[3][2];      // [gate][jj] at x-f4 = s
    #pragma unroll
    for (int g = 0; g < 3; ++g)
        #pragma unroll
        for (int jj = 0; jj < 2; ++jj)
            wiR[g][jj] =
                w_ih4[((size_t)(g * kH + jb * 16 + jp * 2 + jj)) * (kC / 4) + s];

    // biases for this thread's finish output (finishers: even s < 16)
    const int jg_f = jb * 16 + jp * 2 + ((s >> 1) & 1);
    const float brz = b_ih[jg_f]          + b_hh[jg_f];
    const float bzz = b_ih[kH + jg_f]     + b_hh[kH + jg_f];
    const float bxn = b_ih[2 * kH + jg_f];
    const float bhn = b_hh[2 * kH + jg_f];

    unsigned* myflag = flags + grp * kWgPerGrp + jb;
    const unsigned* pollflag = flags + grp * kWgPerGrp + (tid & 31);

    // all-report barrier: store own epoch flag, lanes tid<32 poll all 32
    auto group_barrier = [&](unsigned e) {
        __syncthreads();   // vmcnt(0) drain: prior (atomic) stores MALL-visible
        if (tid < kWgPerGrp) {
            if (tid == 0)
                __hip_atomic_store(myflag, e, __ATOMIC_RELAXED, SCOPE_AGENT);
            unsigned v;
            do {
                v = __hip_atomic_load(pollflag, __ATOMIC_RELAXED, SCOPE_AGENT);
            } while (__any((int)(v < e)));
        }
        __syncthreads();
    };

    for (int t = 0; t < kT; ++t) {
        // ---- stage h rows: PLAIN float4 loads, 2 per thread ----
        {
            #pragma unroll
            for (int qq = 0; qq < 2; ++qq) {
                const int idx = tid + qq * 256;    // 0..511
                const int row = idx >> 7;          // 0..3
                const int f4  = idx & 127;
                float4 v;
                if (t == 0)
                    v = *(const float4*)&h0[(size_t)(b0 + row) * kH + f4 * 4];
                else
                    v = *(const float4*)
                        &hs_out[((size_t)(b0 + row) * kT + (t - 1)) * kH + f4 * 4];
                *(float4*)&hbuf[row][f4 * 4] = v;
            }
        }
        if (t == 0) {   // steady-state x is prefetched at the end of prev iter
            if (tid < 128) {
                const int row = tid >> 5;          // 0..3
                const int f4i = tid & 31;
                *(float4*)&hbuf[row][512 + f4i * 4] =
                    *(const float4*)&x[((size_t)(b0 + row) * kT + 0) * kC + f4i * 4];
            }
        }
        __syncthreads();

        // ---- gate dots: acc[{r,z,n_h,n_x}][4 rows][2 j] ----
        float acc[4][4][2];
        #pragma unroll
        for (int g = 0; g < 4; ++g)
            #pragma unroll
            for (int i = 0; i < 4; ++i) {
                acc[g][i][0] = 0.f; acc[g][i][1] = 0.f;
            }

        const float* hbase = &hbuf[0][s * 4];

        #pragma unroll
        for (int m = 0; m < 4; ++m) {         // h-part: k4 = s + 32m
            const int off = m * 128;
            float4 h4[4];
            #pragma unroll
            for (int i = 0; i < 4; ++i)
                h4[i] = *(const float4*)(hbase + i * kHStride + off);
            #pragma unroll
            for (int g = 0; g < 3; ++g)
                #pragma unroll
                for (int jj = 0; jj < 2; ++jj) {
                    const float4 w4 = whR[m][g][jj];
                    #pragma unroll
                    for (int i = 0; i < 4; ++i)
                        acc[g][i][jj] += h4[i].x * w4.x + h4[i].y * w4.y
                                       + h4[i].z * w4.z + h4[i].w * w4.w;
                }
        }
        {   // x-part: x-f4 = s (weights in registers)
            float4 x4v[4];
            #pragma unroll
            for (int i = 0; i < 4; ++i)
                x4v[i] = *(const float4*)(hbase + i * kHStride + 512);
            #pragma unroll
            for (int g = 0; g < 3; ++g) {
                const int ga = (g == 2) ? 3 : g;   // x-side n goes to acc[3]
                #pragma unroll
                for (int jj = 0; jj < 2; ++jj) {
                    const float4 w4 = wiR[g][jj];
                    #pragma unroll
                    for (int i = 0; i < 4; ++i)
                        acc[ga][i][jj] += x4v[i].x * w4.x + x4v[i].y * w4.y
                                        + x4v[i].z * w4.z + x4v[i].w * w4.w;
                }
            }
        }

        // ---- reduce-scatter over s: xor{8,4,2} + butterflies xor{16,1}.
        // Owner bits: row = b3*2 + b2, jj = b1; bits {0,4} redundant.
        const bool b3 = (s >> 3) & 1;
        const bool b2 = (s >> 2) & 1;
        const bool b1 = (s >> 1) & 1;

        float A[4][2][2];
        #pragma unroll
        for (int g = 0; g < 4; ++g)
            #pragma unroll
            for (int ii = 0; ii < 2; ++ii)
                #pragma unroll
                for (int jj = 0; jj < 2; ++jj) {
                    const float keep = b3 ? acc[g][2 + ii][jj] : acc[g][ii][jj];
                    const float send = b3 ? acc[g][ii][jj] : acc[g][2 + ii][jj];
                    A[g][ii][jj] = keep + __shfl_xor(send, 8);
                }
        float Bv[4][2];
        #pragma unroll
        for (int g = 0; g < 4; ++g)
            #pragma unroll
            for (int jj = 0; jj < 2; ++jj) {
                const float keep = b2 ? A[g][1][jj] : A[g][0][jj];
                const float send = b2 ? A[g][0][jj] : A[g][1][jj];
                Bv[g][jj] = keep + __shfl_xor(send, 4);
            }
        float Dv[4];
        #pragma unroll
        for (int g = 0; g < 4; ++g) {
            const float keep = b1 ? Bv[g][1] : Bv[g][0];
            const float send = b1 ? Bv[g][0] : Bv[g][1];
            float c = keep + __shfl_xor(send, 2);
            c += __shfl_xor(c, 16);
            c += __shfl_xor(c, 1);
            Dv[g] = c;
        }

        __syncthreads();   // all compute reads of hbuf x-section done

        // ---- prefetch x for step t+1 into hbuf x-section ----
        if (t + 1 < kT && tid < 128) {
            const int row = tid >> 5;
            const int f4i = tid & 31;
            *(float4*)&hbuf[row][512 + f4i * 4] =
                *(const float4*)&x[((size_t)(b0 + row) * kT + (t + 1)) * kC + f4i * 4];
        }

        // ---- finish: even lanes s<16 own output (row = b3*2+b2, jj = b1) ----
        if (s < 16 && (s & 1) == 0) {
            const int   row  = ((s >> 3) & 1) * 2 + ((s >> 2) & 1);
            const int   bg   = b0 + row;
            const float rg   = sigmoidf_(Dv[0] + brz);
            const float zg   = sigmoidf_(Dv[1] + bzz);
            const float ng   = tanhf(Dv[3] + bxn + rg * (Dv[2] + bhn));
            const float hold = hbuf[row][jg_f];
            const float hnew = (1.f - zg) * ng + zg * hold;

            // single h-publish: atomic (MALL-visible) store into hs_out
            __hip_atomic_store(&hs_out[((size_t)bg * kT + t) * kH + jg_f], hnew,
                               __ATOMIC_RELAXED, SCOPE_AGENT);
            if (t == kT - 1) h_final[(size_t)bg * kH + jg_f] = hnew;
        }

        group_barrier((unsigned)(t + 1));
    }
}

// In-place post projection: out[b,t,:] = relu(hs[b,t,:] @ w_post^T + b_post).
__global__ __launch_bounds__(256, 1)
void post_kernel(const float* __restrict__ w_post,
                 const float* __restrict__ b_post,
                 float* __restrict__ out)
{
    __shared__ float hbuf[16][kH];
    const int tid = threadIdx.x;
    const size_t row0 = (size_t)blockIdx.x * 16;

    const float4* src = (const float4*)(out + row0 * kH);
    float4* hb4 = (float4*)hbuf;
    for (int i = tid; i < 16 * kH / 4; i += 256) hb4[i] = src[i];
    __syncthreads();

    for (int pass = 0; pass < 2; ++pass) {
        const int d = tid + pass * 256;
        const float4* wrow = (const float4*)(w_post + (size_t)d * kH);
        float acc[16];
        #pragma unroll
        for (int m = 0; m < 16; ++m) acc[m] = 0.f;
        for (int k4 = 0; k4 < kH / 4; ++k4) {
            const float4 w4 = wrow[k4];
            #pragma unroll
            for (int m = 0; m < 16; ++m) {
                const float4 h4 = *(const float4*)&hbuf[m][k4 * 4];
                acc[m] += h4.x * w4.x + h4.y * w4.y + h4.z * w4.z + h4.w * w4.w;
            }
        }
        const float bp = b_post[d];
        #pragma unroll
        for (int m = 0; m < 16; ++m) {
            out[(row0 + m) * kH + d] = fmaxf(acc[m] + bp, 0.f);
        }
    }
}

extern "C" void kernel_launch(void* const* d_in, const int* in_sizes, int n_in,
                              void* d_out, int out_size, void* d_ws, size_t ws_size,
                              hipStream_t stream) {
    const float* x      = (const float*)d_in[0];
    const float* h0     = (const float*)d_in[1];
    const float* w_ih   = (const float*)d_in[2];
    const float* w_hh   = (const float*)d_in[3];
    const float* b_ih   = (const float*)d_in[4];
    const float* b_hh   = (const float*)d_in[5];
    const float* w_post = (const float*)d_in[6];
    const float* b_post = (const float*)d_in[7];

    float* out     = (float*)d_out;
    float* h_final = out + (size_t)kB * kT * kH;

    unsigned* flags = (unsigned*)d_ws;   // 16 x 32 uints = 2 KB

    // flags must start at 0 every launch (d_ws is not re-poisoned per replay)
    hipMemsetAsync(d_ws, 0, 4096, stream);

    void* args[] = { (void*)&x, (void*)&h0, (void*)&w_ih, (void*)&w_hh,
                     (void*)&b_ih, (void*)&b_hh, (void*)&out, (void*)&h_final,
                     (void*)&flags };
    // Cooperative launch for guaranteed co-residency (512 wgs, 2/CU: LDS
    // 2x10.4KB, VGPR capped at 256 by __launch_bounds__(256,2)); fall back
    // to plain launch if refused (2/CU co-resident in practice).
    hipError_t err = hipLaunchCooperativeKernel((void*)gru_seq_kernel,
                                                dim3(512), dim3(256),
                                                args, 0, stream);
    if (err != hipSuccess) {
        gru_seq_kernel<<<dim3(512), dim3(256), 0, stream>>>(
            x, h0, w_ih, w_hh, b_ih, b_hh, out, h_final, flags);
    }

    post_kernel<<<dim3(kB * kT / 16), dim3(256), 0, stream>>>(w_post, b_post, out);
}